// Round 1
// baseline (11673.418 us; speedup 1.0000x reference)
//
#include <hip/hip_runtime.h>

#define B_   64
#define T_   1024
#define IN_  64
#define H_   512
#define OUT_ 64
#define BH   (64*512)   // elements per state slot

typedef _Float16 f16;
typedef _Float16 half8 __attribute__((ext_vector_type(8)));
typedef float    floatx4 __attribute__((ext_vector_type(4)));

#define MFMA16(a,b,c) __builtin_amdgcn_mfma_f32_16x16x32_f16((a),(b),(c),0,0,0)

__device__ __forceinline__ float sigmoidf_(float x) {
    return 1.0f / (1.0f + __expf(-x));
}
__device__ __forceinline__ float tanhf_(float x) {
    float ax = fabsf(x);
    float e  = __expf(-2.0f * ax);
    float t  = (1.0f - e) / (1.0f + e);
    return x >= 0.0f ? t : -t;
}

// ---------------- prep kernels (run every call; weights -> fp16 fragment-linear) ----

// W1p flat = (((g*32 + jt)*18 + kt)*64 + lane)*8 + j
// element = Wcomb1[n = g*512 + jt*16 + (lane&15)][k = kt*32 + (lane>>4)*8 + j]
// Wcomb1[n][k] = k<64 ? W_ih1[n][k] : W_hh1[n][k-64]
__global__ void pack_w1(const float* __restrict__ Wih, const float* __restrict__ Whh,
                        f16* __restrict__ Wp) {
    int idx = blockIdx.x * 256 + threadIdx.x;
    if (idx >= 4*32*18*512) return;
    int j    = idx & 7;
    int lane = (idx >> 3) & 63;
    int kt   = (idx >> 9) % 18;
    int r    = (idx >> 9) / 18;
    int jt   = r & 31;
    int g    = r >> 5;
    int n = g*512 + jt*16 + (lane & 15);
    int k = kt*32 + (lane >> 4)*8 + j;
    float v = (k < 64) ? Wih[n*64 + k] : Whh[n*512 + (k - 64)];
    Wp[idx] = (f16)v;
}

// W2p flat = (((g*32 + jt)*32 + kt)*64 + lane)*8 + j ; K=1024, k<512 -> W_ih2 else W_hh2
__global__ void pack_w2(const float* __restrict__ Wih, const float* __restrict__ Whh,
                        f16* __restrict__ Wp) {
    int idx = blockIdx.x * 256 + threadIdx.x;
    if (idx >= 4*32*32*512) return;
    int j    = idx & 7;
    int lane = (idx >> 3) & 63;
    int kt   = (idx >> 9) & 31;
    int r    = idx >> 14;
    int jt   = r & 31;
    int g    = r >> 5;
    int n = g*512 + jt*16 + (lane & 15);
    int k = kt*32 + (lane >> 4)*8 + j;
    float v = (k < 512) ? Wih[n*512 + k] : Whh[n*512 + (k - 512)];
    Wp[idx] = (f16)v;
}

// Wop flat = ((nt*16 + kt)*64 + lane)*8 + j ; element = W_out[n = nt*16+(lane&15)][k]
__global__ void pack_wo(const float* __restrict__ Wout, f16* __restrict__ Wp) {
    int idx = blockIdx.x * 256 + threadIdx.x;
    if (idx >= 4*16*512) return;
    int j    = idx & 7;
    int lane = (idx >> 3) & 63;
    int kt   = (idx >> 9) & 15;
    int nt   = idx >> 13;
    int n = nt*16 + (lane & 15);
    int k = kt*32 + (lane >> 4)*8 + j;
    Wp[idx] = (f16)Wout[n*512 + k];
}

__global__ void bias_sum(const float* __restrict__ a1, const float* __restrict__ b1,
                         const float* __restrict__ a2, const float* __restrict__ b2,
                         float* __restrict__ s1, float* __restrict__ s2) {
    int i = blockIdx.x * 256 + threadIdx.x;
    if (i >= 2048) return;
    s1[i] = a1[i] + b1[i];
    s2[i] = a2[i] + b2[i];
}

// ---------------- phase kernel ----------------
// phase p: blocks 0..31  -> layer1 step t=p        (active p in [0,1023])
//          blocks 32..63 -> layer2 step t2=p-1     (active p in [1,1024])
//          block  64     -> head   step t3=p-2     (active p in [2,1025])
// Waves: wave = (kh<<2)|mt; wave handles m-tile mt (16 batches) over k-half kh.
// MFMA 16x16x32 f16. A: lane holds A[m=lane&15][k=quad*8+j]. B: B[k][n=lane&15],
// k=quad*8+j (pre-swizzled, lane*16B contiguous). C/D: col=lane&15, row=quad*4+reg.
__global__ __launch_bounds__(512) void lstm_phase(
    int p,
    const float* __restrict__ x,
    const f16*  __restrict__ W1p,
    const f16*  __restrict__ W2p,
    const f16*  __restrict__ Wop,
    const float* __restrict__ bs1,
    const float* __restrict__ bs2,
    const float* __restrict__ bout,
    f16*  __restrict__ h1buf,   // [2][64][512] fp16
    f16*  __restrict__ h2buf,   // [2][64][512] fp16
    float* __restrict__ c1buf,  // [2][64][512] fp32
    float* __restrict__ c2buf,  // [2][64][512] fp32
    float* __restrict__ y)      // [64][1024][64] fp32
{
    __shared__ float red[4096];  // 16 KB k-split reduction buffer

    const int wg   = blockIdx.x;
    const int tid  = threadIdx.x;
    const int lane = tid & 63;
    const int wave = tid >> 6;
    const int mt   = wave & 3;
    const int kh   = wave >> 2;
    const int col  = lane & 15;
    const int quad = lane >> 4;

    floatx4 acc0 = {0.f,0.f,0.f,0.f};
    floatx4 acc1 = {0.f,0.f,0.f,0.f};
    floatx4 acc2 = {0.f,0.f,0.f,0.f};
    floatx4 acc3 = {0.f,0.f,0.f,0.f};

    if (wg < 32) {
        // ---------------- layer 1, t = p ----------------
        const int t = p;
        if (t >= T_) return;
        const int jt = wg;
        const int sR = (p + 1) & 1;   // slot of h1[t-1], c1[t-1]  ((p-1)&1)
        const int sW = p & 1;         // slot of h1[t],  c1[t]
        const int b  = mt*16 + col;

        const int kt0 = kh * 9, kt1 = kt0 + 9;   // 18 k-tiles of 32 (K=576)
        for (int kt = kt0; kt < kt1; ++kt) {
            half8 a;
            if (kt < 2) {   // x part: k in [0,64)
                const float* xp = x + ((size_t)b*T_ + t)*IN_ + kt*32 + quad*8;
                float4 u = *(const float4*)xp;
                float4 v = *(const float4*)(xp + 4);
                a = (half8){(f16)u.x,(f16)u.y,(f16)u.z,(f16)u.w,
                            (f16)v.x,(f16)v.y,(f16)v.z,(f16)v.w};
            } else {        // h1[t-1] part
                a = *(const half8*)(h1buf + sR*BH + b*H_ + (kt*32 + quad*8 - 64));
            }
            const f16* wb = W1p + ((size_t)(jt*18 + kt)*64 + lane)*8;
            acc0 = MFMA16(a, *(const half8*)(wb            ), acc0);
            acc1 = MFMA16(a, *(const half8*)(wb + 1*32*18*512), acc1);
            acc2 = MFMA16(a, *(const half8*)(wb + 2*32*18*512), acc2);
            acc3 = MFMA16(a, *(const half8*)(wb + 3*32*18*512), acc3);
        }
        if (kh == 1) {
            for (int r = 0; r < 4; ++r) {
                red[((mt*4+0)*16 + quad*4 + r)*16 + col] = acc0[r];
                red[((mt*4+1)*16 + quad*4 + r)*16 + col] = acc1[r];
                red[((mt*4+2)*16 + quad*4 + r)*16 + col] = acc2[r];
                red[((mt*4+3)*16 + quad*4 + r)*16 + col] = acc3[r];
            }
        }
        __syncthreads();
        if (kh == 0) {
            const int jh = jt*16 + col;
            for (int r = 0; r < 4; ++r) {
                const int bb = mt*16 + quad*4 + r;
                float gi = acc0[r] + red[((mt*4+0)*16 + quad*4 + r)*16 + col] + bs1[jh];
                float gf = acc1[r] + red[((mt*4+1)*16 + quad*4 + r)*16 + col] + bs1[512 + jh];
                float gg = acc2[r] + red[((mt*4+2)*16 + quad*4 + r)*16 + col] + bs1[1024 + jh];
                float go = acc3[r] + red[((mt*4+3)*16 + quad*4 + r)*16 + col] + bs1[1536 + jh];
                float i_ = sigmoidf_(gi);
                float f_ = sigmoidf_(gf);
                float g_ = tanhf_(gg);
                float o_ = sigmoidf_(go);
                float cn = f_ * c1buf[sR*BH + bb*H_ + jh] + i_ * g_;
                c1buf[sW*BH + bb*H_ + jh] = cn;
                h1buf[sW*BH + bb*H_ + jh] = (f16)(o_ * tanhf_(cn));
            }
        }
    } else if (wg < 64) {
        // ---------------- layer 2, t2 = p-1 ----------------
        const int t2 = p - 1;
        if (t2 < 0 || t2 >= T_) return;
        const int jt  = wg - 32;
        const int sH1 = (p + 1) & 1;  // h1[t2] slot
        const int sR  = p & 1;        // h2[t2-1], c2[t2-1] slot
        const int sW  = (p + 1) & 1;  // h2[t2], c2[t2] slot
        const int b   = mt*16 + col;

        const int kt0 = kh * 16, kt1 = kt0 + 16;  // 32 k-tiles (K=1024)
        for (int kt = kt0; kt < kt1; ++kt) {
            const int k = kt*32 + quad*8;
            half8 a;
            if (k < 512) a = *(const half8*)(h1buf + sH1*BH + b*H_ + k);
            else         a = *(const half8*)(h2buf + sR*BH  + b*H_ + (k - 512));
            const f16* wb = W2p + ((size_t)(jt*32 + kt)*64 + lane)*8;
            acc0 = MFMA16(a, *(const half8*)(wb            ), acc0);
            acc1 = MFMA16(a, *(const half8*)(wb + 1*32*32*512), acc1);
            acc2 = MFMA16(a, *(const half8*)(wb + 2*32*32*512), acc2);
            acc3 = MFMA16(a, *(const half8*)(wb + 3*32*32*512), acc3);
        }
        if (kh == 1) {
            for (int r = 0; r < 4; ++r) {
                red[((mt*4+0)*16 + quad*4 + r)*16 + col] = acc0[r];
                red[((mt*4+1)*16 + quad*4 + r)*16 + col] = acc1[r];
                red[((mt*4+2)*16 + quad*4 + r)*16 + col] = acc2[r];
                red[((mt*4+3)*16 + quad*4 + r)*16 + col] = acc3[r];
            }
        }
        __syncthreads();
        if (kh == 0) {
            const int jh = jt*16 + col;
            for (int r = 0; r < 4; ++r) {
                const int bb = mt*16 + quad*4 + r;
                float gi = acc0[r] + red[((mt*4+0)*16 + quad*4 + r)*16 + col] + bs2[jh];
                float gf = acc1[r] + red[((mt*4+1)*16 + quad*4 + r)*16 + col] + bs2[512 + jh];
                float gg = acc2[r] + red[((mt*4+2)*16 + quad*4 + r)*16 + col] + bs2[1024 + jh];
                float go = acc3[r] + red[((mt*4+3)*16 + quad*4 + r)*16 + col] + bs2[1536 + jh];
                float i_ = sigmoidf_(gi);
                float f_ = sigmoidf_(gf);
                float g_ = tanhf_(gg);
                float o_ = sigmoidf_(go);
                float cn = f_ * c2buf[sR*BH + bb*H_ + jh] + i_ * g_;
                c2buf[sW*BH + bb*H_ + jh] = cn;
                h2buf[sW*BH + bb*H_ + jh] = (f16)(o_ * tanhf_(cn));
            }
        }
    } else {
        // ---------------- head, t3 = p-2 ----------------
        const int t3 = p - 2;
        if (t3 < 0 || t3 >= T_) return;
        const int sH = p & 1;  // h2[t3] slot ((p-2)&1)
        const int b  = mt*16 + col;

        const int kt0 = kh * 8, kt1 = kt0 + 8;   // 16 k-tiles (K=512)
        for (int kt = kt0; kt < kt1; ++kt) {
            half8 a = *(const half8*)(h2buf + sH*BH + b*H_ + kt*32 + quad*8);
            const f16* wb = Wop + ((size_t)kt*64 + lane)*8;
            acc0 = MFMA16(a, *(const half8*)(wb         ), acc0);   // nt stride 16*64*8=8192
            acc1 = MFMA16(a, *(const half8*)(wb +   8192), acc1);
            acc2 = MFMA16(a, *(const half8*)(wb + 2*8192), acc2);
            acc3 = MFMA16(a, *(const half8*)(wb + 3*8192), acc3);
        }
        if (kh == 1) {
            for (int r = 0; r < 4; ++r) {
                red[((mt*4+0)*16 + quad*4 + r)*16 + col] = acc0[r];
                red[((mt*4+1)*16 + quad*4 + r)*16 + col] = acc1[r];
                red[((mt*4+2)*16 + quad*4 + r)*16 + col] = acc2[r];
                red[((mt*4+3)*16 + quad*4 + r)*16 + col] = acc3[r];
            }
        }
        __syncthreads();
        if (kh == 0) {
            for (int r = 0; r < 4; ++r) {
                const int bb = mt*16 + quad*4 + r;
                const size_t base = ((size_t)bb*T_ + t3)*OUT_;
                y[base +  0 + col] = acc0[r] + red[((mt*4+0)*16 + quad*4 + r)*16 + col] + bout[ 0 + col];
                y[base + 16 + col] = acc1[r] + red[((mt*4+1)*16 + quad*4 + r)*16 + col] + bout[16 + col];
                y[base + 32 + col] = acc2[r] + red[((mt*4+2)*16 + quad*4 + r)*16 + col] + bout[32 + col];
                y[base + 48 + col] = acc3[r] + red[((mt*4+3)*16 + quad*4 + r)*16 + col] + bout[48 + col];
            }
        }
    }
}

// ---------------- launch ----------------
extern "C" void kernel_launch(void* const* d_in, const int* in_sizes, int n_in,
                              void* d_out, int out_size, void* d_ws, size_t ws_size,
                              hipStream_t stream) {
    const float* x    = (const float*)d_in[0];
    const float* Wih1 = (const float*)d_in[1];
    const float* Whh1 = (const float*)d_in[2];
    const float* bih1 = (const float*)d_in[3];
    const float* bhh1 = (const float*)d_in[4];
    const float* Wih2 = (const float*)d_in[5];
    const float* Whh2 = (const float*)d_in[6];
    const float* bih2 = (const float*)d_in[7];
    const float* bhh2 = (const float*)d_in[8];
    const float* Wout = (const float*)d_in[9];
    const float* bout = (const float*)d_in[10];
    float* y = (float*)d_out;

    // workspace layout (7,421,952 bytes total; all offsets 256B-aligned)
    char* ws = (char*)d_ws;
    f16*   W1p   = (f16*)(ws + 0);                 // 4*32*18*512 fp16 = 2,359,296 B
    f16*   W2p   = (f16*)(ws + 2359296);           // 4*32*32*512 fp16 = 4,194,304 B
    f16*   Wop   = (f16*)(ws + 6553600);           // 4*16*512 fp16    =    65,536 B
    float* bs1   = (float*)(ws + 6619136);         // 2048 fp32        =     8,192 B
    float* bs2   = (float*)(ws + 6627328);         // 2048 fp32        =     8,192 B
    f16*   h1buf = (f16*)(ws + 6635520);           // 2*64*512 fp16    =   131,072 B
    f16*   h2buf = (f16*)(ws + 6766592);           // 2*64*512 fp16    =   131,072 B
    float* c1buf = (float*)(ws + 6897664);         // 2*64*512 fp32    =   262,144 B
    float* c2buf = (float*)(ws + 7159808);         // 2*64*512 fp32    =   262,144 B

    // zero all state (slot-1 buffers are the t=-1 initial states)
    hipMemsetAsync(ws + 6635520, 0, 786432, stream);

    pack_w1<<<4608, 256, 0, stream>>>(Wih1, Whh1, W1p);
    pack_w2<<<8192, 256, 0, stream>>>(Wih2, Whh2, W2p);
    pack_wo<<<128, 256, 0, stream>>>(Wout, Wop);
    bias_sum<<<8, 256, 0, stream>>>(bih1, bhh1, bih2, bhh2, bs1, bs2);

    for (int p = 0; p < T_ + 2; ++p) {
        lstm_phase<<<65, 512, 0, stream>>>(p, x, W1p, W2p, Wop, bs1, bs2, bout,
                                           h1buf, h2buf, c1buf, c2buf, y);
    }
}